// Round 3
// baseline (311.277 us; speedup 1.0000x reference)
//
#include <hip/hip_runtime.h>
#include <hip/hip_bf16.h>

// Problem constants (from reference setup_inputs)
constexpr int B = 128;
constexpr int A = 8732;
constexpr int C = 21;
constexpr int M = 8;

// ---------------------------------------------------------------------------
// K0: zero accumulators
// accf[0]=conf_pos, accf[1]=loc_sum, accf[2]=conf_hard_neg ; npt = n_pos_total
__global__ void k_init(float* accf, int* npt) {
    int t = threadIdx.x;
    if (t < 3) accf[t] = 0.f;
    if (t == 3) *npt = 0;
}

// ---------------------------------------------------------------------------
// K1: per-batch matching. One block (1024 threads) per batch row.
__global__ __launch_bounds__(1024) void k_match(
    const float* __restrict__ boxes,    // [B,M,4] raw pixel xy
    const int*   __restrict__ labels,   // [B,M]
    const float* __restrict__ anchors,  // [A,4] cxcy
    int*         __restrict__ packed,   // [B,A]  lab | (obj<<8)
    int*         __restrict__ n_pos,    // [B]
    int*         __restrict__ npt)
{
    __shared__ float         s_iou[A];
    __shared__ unsigned char s_obj[A];
    __shared__ float s_pv[M][16];
    __shared__ int   s_pi[M][16];
    __shared__ int   s_force[M];
    __shared__ int   s_c[16];
    __shared__ float s_box[M][4];
    __shared__ int   s_lab[M];

    const int b = blockIdx.x;
    const int t = threadIdx.x;
    const int lane = t & 63;
    const int wv   = t >> 6;          // 0..15

    if (t < M * 4) ((float*)s_box)[t] = boxes[b * M * 4 + t];
    if (t < M)     s_lab[t] = labels[b * M + t];
    __syncthreads();

    // scaled boxes (match reference: boxes / 300.0) + areas
    float bb[M][4], barea[M];
#pragma unroll
    for (int m = 0; m < M; m++) {
        bb[m][0] = s_box[m][0] / 300.f;
        bb[m][1] = s_box[m][1] / 300.f;
        bb[m][2] = s_box[m][2] / 300.f;
        bb[m][3] = s_box[m][3] / 300.f;
        barea[m] = (bb[m][2] - bb[m][0]) * (bb[m][3] - bb[m][1]);
    }

    float bestv[M];
    int   besti[M];
#pragma unroll
    for (int m = 0; m < M; m++) { bestv[m] = -1.f; besti[m] = 0; }

    const float4* anch4 = (const float4*)anchors;
    for (int a = t; a < A; a += 1024) {
        float4 an = anch4[a];
        float ax1 = an.x - an.z / 2.0f, ay1 = an.y - an.w / 2.0f;
        float ax2 = an.x + an.z / 2.0f, ay2 = an.y + an.w / 2.0f;
        float aarea = (ax2 - ax1) * (ay2 - ay1);

        float bmax = -1.f; int bm = 0;
#pragma unroll
        for (int m = 0; m < M; m++) {
            float lx = fmaxf(bb[m][0], ax1), ly = fmaxf(bb[m][1], ay1);
            float rx = fminf(bb[m][2], ax2), ry = fminf(bb[m][3], ay2);
            float iw = fmaxf(rx - lx, 0.f), ih = fmaxf(ry - ly, 0.f);
            float inter = iw * ih;
            float iou = inter / (barea[m] + aarea - inter);
            if (iou > bmax) { bmax = iou; bm = m; }               // first-max over m
            if (iou > bestv[m]) { bestv[m] = iou; besti[m] = a; } // first-max over a (ascending)
        }
        s_iou[a] = bmax;
        s_obj[a] = (unsigned char)bm;
    }

    // per-object argmax: wave shuffle reduce (tie-break: smaller anchor index)
#pragma unroll
    for (int m = 0; m < M; m++) {
        float v = bestv[m]; int i = besti[m];
        for (int off = 32; off > 0; off >>= 1) {
            float ov = __shfl_down(v, off);
            int   oi = __shfl_down(i, off);
            if (ov > v || (ov == v && oi < i)) { v = ov; i = oi; }
        }
        if (lane == 0) { s_pv[m][wv] = v; s_pi[m][wv] = i; }
    }
    __syncthreads();

    if (t < M) {
        float bv = -1.f; int bi = 0x7fffffff;
#pragma unroll
        for (int w = 0; w < 16; w++) {
            float v = s_pv[t][w]; int i = s_pi[t][w];
            if (v > bv || (v == bv && i < bi)) { bv = v; bi = i; }
        }
        s_force[t] = bi;
    }
    __syncthreads();

    // numpy fancy-assign semantics: last object wins on duplicate anchors
    if (t == 0) {
        for (int m = 0; m < M; m++) {
            int a = s_force[m];
            s_obj[a] = (unsigned char)m;
            s_iou[a] = 1.0f;
        }
    }
    __syncthreads();

    int cnt = 0;
    for (int a = t; a < A; a += 1024) {
        int obj = s_obj[a];
        int lab = s_lab[obj];
        if (s_iou[a] < 0.5f) lab = 0;
        packed[(size_t)b * A + a] = lab | (obj << 8);
        if (lab != 0) cnt++;
    }
    for (int off = 32; off > 0; off >>= 1) cnt += __shfl_down(cnt, off);
    if (lane == 0) s_c[wv] = cnt;
    __syncthreads();
    if (t == 0) {
        int c0 = 0;
#pragma unroll
        for (int w = 0; w < 16; w++) c0 += s_c[w];
        n_pos[b] = c0;
        atomicAdd(npt, c0);
    }
}

// ---------------------------------------------------------------------------
// K2: per-anchor CE + positive loc L1.
// Round-2 post-mortem: quad-per-thread layout was latency-bound (~750 cy per
// VMEM instr, ~1KB in flight per CU) — every dwordx4 spanned 64 cache lines
// and the 64-VGPR schedule serialized dependent load chunks.
// New structure: wave-cooperative + software-pipelined, NO barriers.
//  - each wave owns 4 consecutive groups of 64 anchors (21KB contiguous)
//  - per group: 6 coalesced float4 loads/lane (1KB per instruction), double
//    buffered in registers: group k+1's loads issue BEFORE consuming group k,
//    so ~6KB/wave stays in flight continuously (T14 issue-early/write-late)
//  - registers -> per-wave private LDS strip (5376B) -> per-anchor rows.
//    Wave-lockstep write->lgkmcnt(0)->read needs no __syncthreads.
//  - LDS read stride 21 floats: gcd(21,32)=1 -> 2 lanes/bank = conflict-free.
__global__ __launch_bounds__(256, 4) void k_ce(
    const float* __restrict__ plocs,    // [B,A,4]
    const float* __restrict__ pscores,  // [B,A,C]
    const float* __restrict__ boxes,    // [B,M,4] raw pixel xy
    const float* __restrict__ anchors,  // [A,4]
    int*         __restrict__ buf,      // in: packed, out: ce_neg bits
    float*       __restrict__ accf)
{
    __shared__ float s[4][21 * 64];     // 4 waves x 5376 B = 21504 B
    const int t    = threadIdx.x;
    const int lane = t & 63;
    const int wv   = t >> 6;
    const int gw   = blockIdx.x * 4 + wv;      // global wave id
    constexpr int NGW = (B * A / 64) / 4;      // 4366 active waves (exact)

    float l_pos = 0.f, l_loc = 0.f;

    if (gw < NGW) {                            // wave-uniform guard
        float* sw = s[wv];
        const int g0 = gw * 4;                 // first of 4 groups, all valid
        const float4* ps4 = (const float4*)pscores;

        float4 ra[6], rb[6];
        int pka = 0, pkb = 0;

        // prologue: prefetch group g0 (scores + packed labels)
        {
            const float4* base = ps4 + (size_t)g0 * 336;
#pragma unroll
            for (int q = 0; q < 5; ++q) ra[q] = base[lane + q * 64];
            if (lane < 16) ra[5] = base[320 + lane];
            pka = buf[g0 * 64 + lane];
        }

#pragma unroll
        for (int k = 0; k < 4; ++k) {
            const int g = g0 + k;

            // issue next group's loads first (stay in flight during compute)
            if (k < 3) {
                const float4* base = ps4 + (size_t)(g + 1) * 336;
                if (k & 1) {
#pragma unroll
                    for (int q = 0; q < 5; ++q) ra[q] = base[lane + q * 64];
                    if (lane < 16) ra[5] = base[320 + lane];
                    pka = buf[(g + 1) * 64 + lane];
                } else {
#pragma unroll
                    for (int q = 0; q < 5; ++q) rb[q] = base[lane + q * 64];
                    if (lane < 16) rb[5] = base[320 + lane];
                    pkb = buf[(g + 1) * 64 + lane];
                }
            }
            const int pk = (k & 1) ? pkb : pka;

            // ensure previous iteration's ds_reads drained before overwrite
            asm volatile("s_waitcnt lgkmcnt(0)" ::: "memory");
            if (k & 1) {
#pragma unroll
                for (int q = 0; q < 5; ++q) ((float4*)sw)[lane + q * 64] = rb[q];
                if (lane < 16) ((float4*)sw)[320 + lane] = rb[5];
            } else {
#pragma unroll
                for (int q = 0; q < 5; ++q) ((float4*)sw)[lane + q * 64] = ra[q];
                if (lane < 16) ((float4*)sw)[320 + lane] = ra[5];
            }
            asm volatile("s_waitcnt lgkmcnt(0)" ::: "memory");

            // per-anchor row from LDS (stride 21 floats: conflict-free)
            const float* row = sw + lane * 21;
            float v[21];
#pragma unroll
            for (int c = 0; c < 21; ++c) v[c] = row[c];

            const int lab = pk & 255;
            const int obj = pk >> 8;

            float mx = v[0];
#pragma unroll
            for (int c = 1; c < 21; ++c) mx = fmaxf(mx, v[c]);
            float sum = 0.f, slab = 0.f;
#pragma unroll
            for (int c = 0; c < 21; ++c) {
                sum += __expf(v[c] - mx);
                if (c == lab) slab = v[c];   // static compare, no dyn index
            }
            const float ce = mx + __logf(sum) - slab;

            const int flat = g * 64 + lane;
            float cn = ce;
            if (lab != 0) {
                cn = 0.f;
                l_pos += ce;
                const int bi = flat / A;
                const int ai = flat - bi * A;
                const float* bx = boxes + ((size_t)bi * M + obj) * 4;
                const float* an = anchors + (size_t)ai * 4;
                // reference quirk: raw pixel xy boxes fed into cxcy_to_gcxgcy
                float dx = (bx[0] - an[0]) / (an[2] / 10.f);
                float dy = (bx[1] - an[1]) / (an[3] / 10.f);
                float dw = logf(bx[2] / an[2]) * 5.f;
                float dh = logf(bx[3] / an[3]) * 5.f;
                float4 p = ((const float4*)plocs)[flat];
                l_loc += fabsf(p.x - dx) + fabsf(p.y - dy) +
                         fabsf(p.z - dw) + fabsf(p.w - dh);
            }
            ((float*)buf)[flat] = cn;        // coalesced dword store
        }
    }

    // wave reduce; idle waves contribute zero and skip the atomic
    for (int off = 32; off > 0; off >>= 1) {
        l_pos += __shfl_down(l_pos, off);
        l_loc += __shfl_down(l_loc, off);
    }
    if ((t & 63) == 0 && (l_pos != 0.f || l_loc != 0.f)) {
        atomicAdd(&accf[0], l_pos);
        atomicAdd(&accf[1], l_loc);
    }
}

// ---------------------------------------------------------------------------
// K3: per-row sum of top-(3*n_pos[b]) of ce_neg via radix select.
// Exact even with ties: sum = sum(v>t) + (K - cnt_gt) * t.
__global__ __launch_bounds__(1024) void k_topk(
    const float* __restrict__ ce_neg,   // [B,A] (aliased buf)
    const int*   __restrict__ n_pos,    // [B]
    float*       __restrict__ accf)     // accf[2] += row topK sum
{
    __shared__ unsigned int vals[A];
    __shared__ unsigned int hist[256];  // histogram, then suffix sums
    __shared__ unsigned int s_prefix, s_krem;
    __shared__ float        rs[16];
    __shared__ unsigned int rc[16];

    const int b = blockIdx.x;
    const int t = threadIdx.x;
    const int lane = t & 63;
    const int wv   = t >> 6;
    const int K = 3 * n_pos[b];
    const float* row = ce_neg + (size_t)b * A;

    {   // coalesced uint4 load (A = 4*2183, row base 16B-aligned)
        const uint4* r4 = (const uint4*)row;
        uint4* v4 = (uint4*)vals;
        for (int i = t; i < A / 4; i += 1024) v4[i] = r4[i];
    }
    if (t == 0) { s_prefix = 0u; s_krem = (unsigned)K; }
    __syncthreads();

    if (K <= 0) return;  // uniform branch

    if (K >= A) {        // uniform branch: sum the whole row
        float s = 0.f;
        for (int i = t; i < A; i += 1024) s += __uint_as_float(vals[i]);
        for (int off = 32; off > 0; off >>= 1) s += __shfl_down(s, off);
        if (lane == 0) rs[wv] = s;
        __syncthreads();
        if (t == 0) {
            float tot = 0.f;
#pragma unroll
            for (int w = 0; w < 16; w++) tot += rs[w];
            atomicAdd(&accf[2], tot);
        }
        return;
    }

    for (int pass = 0; pass < 4; pass++) {
        const int shift = 24 - 8 * pass;
        const unsigned pref = s_prefix;
        const unsigned krem = s_krem;
        if (t < 256) hist[t] = 0u;
        __syncthreads();
        for (int i = t; i < A; i += 1024) {
            unsigned int v = vals[i];
            if (pass == 0 || (v >> (shift + 8)) == pref)
                atomicAdd(&hist[(v >> shift) & 255u], 1u);
        }
        __syncthreads();
        // wave-0 suffix scan of the 256 bins (hist[i] := sum hist[i..255])
        if (t < 64) {
            unsigned h0 = hist[4 * t + 0], h1 = hist[4 * t + 1];
            unsigned h2 = hist[4 * t + 2], h3 = hist[4 * t + 3];
            unsigned s3 = h3, s2 = h2 + s3, s1 = h1 + s2, s0 = h0 + s1;
            unsigned suf = s0;                 // inclusive suffix of lane totals
            for (int off = 1; off < 64; off <<= 1) {
                unsigned o = __shfl_down(suf, off);
                if (t + off < 64) suf += o;
            }
            unsigned above = suf - s0;         // totals of lanes > t
            hist[4 * t + 0] = above + s0;
            hist[4 * t + 1] = above + s1;
            hist[4 * t + 2] = above + s2;
            hist[4 * t + 3] = above + s3;
        }
        __syncthreads();
        if (t < 256) {
            unsigned ssT = hist[t];
            unsigned ssN = (t < 255) ? hist[t + 1] : 0u;
            if (ssT >= krem && ssN < krem) {   // exactly one thread
                s_prefix = (pref << 8) | (unsigned)t;
                s_krem   = krem - ssN;
            }
        }
        __syncthreads();
    }

    const unsigned int tb = s_prefix;  // bits of the K-th largest value
    float sg = 0.f; unsigned int cg = 0;
    for (int i = t; i < A; i += 1024) {
        unsigned int v = vals[i];
        if (v > tb) { sg += __uint_as_float(v); cg++; }
    }
    for (int off = 32; off > 0; off >>= 1) {
        sg += __shfl_down(sg, off);
        cg += __shfl_down(cg, off);
    }
    if (lane == 0) { rs[wv] = sg; rc[wv] = cg; }
    __syncthreads();
    if (t == 0) {
        float tv = __uint_as_float(tb);
        float tot = 0.f; unsigned cnt = 0;
#pragma unroll
        for (int w = 0; w < 16; w++) { tot += rs[w]; cnt += rc[w]; }
        atomicAdd(&accf[2], tot + (float)(K - (int)cnt) * tv);
    }
}

// ---------------------------------------------------------------------------
// K4: final scalar
__global__ void k_final(const float* __restrict__ accf,
                        const int* __restrict__ npt,
                        float* __restrict__ out)
{
    float n = (float)(*npt);
    float conf_loss = (accf[2] + accf[0]) / n;
    float loc_loss  = accf[1] / (n * 4.f);
    out[0] = conf_loss + loc_loss;
}

// ---------------------------------------------------------------------------
extern "C" void kernel_launch(void* const* d_in, const int* in_sizes, int n_in,
                              void* d_out, int out_size, void* d_ws, size_t ws_size,
                              hipStream_t stream)
{
    const float* plocs   = (const float*)d_in[0];  // [B,A,4]
    const float* pscores = (const float*)d_in[1];  // [B,A,C]
    const float* boxes   = (const float*)d_in[2];  // [B,M,4]
    const int*   labels  = (const int*)d_in[3];    // [B,M]
    const float* anchors = (const float*)d_in[4];  // [A,4]
    float*       out     = (float*)d_out;

    // workspace layout (4-byte elements):
    // [0..2] accf, [3] n_pos_total, [8..8+B) n_pos, [8+B ..) packed/ce_neg [B*A]
    // buf offset = (8+B)*4 = 544 bytes -> 16B-aligned for int4/float4 access
    float* accf  = (float*)d_ws;
    int*   npt   = (int*)d_ws + 3;
    int*   n_pos = (int*)d_ws + 8;
    int*   buf   = (int*)d_ws + 8 + B;

    k_init<<<1, 64, 0, stream>>>(accf, npt);
    k_match<<<B, 1024, 0, stream>>>(boxes, labels, anchors, buf, n_pos, npt);
    constexpr int NBW = ((B * A / 64) / 4 + 3) / 4;   // 1092 blocks of 4 waves
    k_ce<<<NBW, 256, 0, stream>>>(plocs, pscores, boxes, anchors, buf, accf);
    k_topk<<<B, 1024, 0, stream>>>((const float*)buf, n_pos, accf);
    k_final<<<1, 1, 0, stream>>>(accf, npt, out);
}

// Round 5
// 294.765 us; speedup vs baseline: 1.0560x; 1.0560x over previous
//
#include <hip/hip_runtime.h>
#include <hip/hip_bf16.h>

// Problem constants (from reference setup_inputs)
constexpr int B = 128;
constexpr int A = 8732;
constexpr int C = 21;
constexpr int M = 8;

// ---------------------------------------------------------------------------
// K0: zero accumulators
// accf[0]=conf_pos, accf[1]=loc_sum, accf[2]=conf_hard_neg ; npt = n_pos_total
__global__ void k_init(float* accf, int* npt) {
    int t = threadIdx.x;
    if (t < 3) accf[t] = 0.f;
    if (t == 3) *npt = 0;
}

// ---------------------------------------------------------------------------
// K1: per-batch matching. One block (1024 threads) per batch row.
__global__ __launch_bounds__(1024) void k_match(
    const float* __restrict__ boxes,    // [B,M,4] raw pixel xy
    const int*   __restrict__ labels,   // [B,M]
    const float* __restrict__ anchors,  // [A,4] cxcy
    int*         __restrict__ packed,   // [B,A]  lab | (obj<<8)
    int*         __restrict__ n_pos,    // [B]
    int*         __restrict__ npt)
{
    __shared__ float         s_iou[A];
    __shared__ unsigned char s_obj[A];
    __shared__ float s_pv[M][16];
    __shared__ int   s_pi[M][16];
    __shared__ int   s_force[M];
    __shared__ int   s_c[16];
    __shared__ float s_box[M][4];
    __shared__ int   s_lab[M];

    const int b = blockIdx.x;
    const int t = threadIdx.x;
    const int lane = t & 63;
    const int wv   = t >> 6;          // 0..15

    if (t < M * 4) ((float*)s_box)[t] = boxes[b * M * 4 + t];
    if (t < M)     s_lab[t] = labels[b * M + t];
    __syncthreads();

    // scaled boxes (match reference: boxes / 300.0) + areas
    float bb[M][4], barea[M];
#pragma unroll
    for (int m = 0; m < M; m++) {
        bb[m][0] = s_box[m][0] / 300.f;
        bb[m][1] = s_box[m][1] / 300.f;
        bb[m][2] = s_box[m][2] / 300.f;
        bb[m][3] = s_box[m][3] / 300.f;
        barea[m] = (bb[m][2] - bb[m][0]) * (bb[m][3] - bb[m][1]);
    }

    float bestv[M];
    int   besti[M];
#pragma unroll
    for (int m = 0; m < M; m++) { bestv[m] = -1.f; besti[m] = 0; }

    const float4* anch4 = (const float4*)anchors;
    for (int a = t; a < A; a += 1024) {
        float4 an = anch4[a];
        float ax1 = an.x - an.z / 2.0f, ay1 = an.y - an.w / 2.0f;
        float ax2 = an.x + an.z / 2.0f, ay2 = an.y + an.w / 2.0f;
        float aarea = (ax2 - ax1) * (ay2 - ay1);

        float bmax = -1.f; int bm = 0;
#pragma unroll
        for (int m = 0; m < M; m++) {
            float lx = fmaxf(bb[m][0], ax1), ly = fmaxf(bb[m][1], ay1);
            float rx = fminf(bb[m][2], ax2), ry = fminf(bb[m][3], ay2);
            float iw = fmaxf(rx - lx, 0.f), ih = fmaxf(ry - ly, 0.f);
            float inter = iw * ih;
            float iou = inter / (barea[m] + aarea - inter);
            if (iou > bmax) { bmax = iou; bm = m; }               // first-max over m
            if (iou > bestv[m]) { bestv[m] = iou; besti[m] = a; } // first-max over a (ascending)
        }
        s_iou[a] = bmax;
        s_obj[a] = (unsigned char)bm;
    }

    // per-object argmax: wave shuffle reduce (tie-break: smaller anchor index)
#pragma unroll
    for (int m = 0; m < M; m++) {
        float v = bestv[m]; int i = besti[m];
        for (int off = 32; off > 0; off >>= 1) {
            float ov = __shfl_down(v, off);
            int   oi = __shfl_down(i, off);
            if (ov > v || (ov == v && oi < i)) { v = ov; i = oi; }
        }
        if (lane == 0) { s_pv[m][wv] = v; s_pi[m][wv] = i; }
    }
    __syncthreads();

    if (t < M) {
        float bv = -1.f; int bi = 0x7fffffff;
#pragma unroll
        for (int w = 0; w < 16; w++) {
            float v = s_pv[t][w]; int i = s_pi[t][w];
            if (v > bv || (v == bv && i < bi)) { bv = v; bi = i; }
        }
        s_force[t] = bi;
    }
    __syncthreads();

    // numpy fancy-assign semantics: last object wins on duplicate anchors
    if (t == 0) {
        for (int m = 0; m < M; m++) {
            int a = s_force[m];
            s_obj[a] = (unsigned char)m;
            s_iou[a] = 1.0f;
        }
    }
    __syncthreads();

    int cnt = 0;
    for (int a = t; a < A; a += 1024) {
        int obj = s_obj[a];
        int lab = s_lab[obj];
        if (s_iou[a] < 0.5f) lab = 0;
        packed[(size_t)b * A + a] = lab | (obj << 8);
        if (lab != 0) cnt++;
    }
    for (int off = 32; off > 0; off >>= 1) cnt += __shfl_down(cnt, off);
    if (lane == 0) s_c[wv] = cnt;
    __syncthreads();
    if (t == 0) {
        int c0 = 0;
#pragma unroll
        for (int w = 0; w < 16; w++) c0 += s_c[w];
        n_pos[b] = c0;
        atomicAdd(npt, c0);
    }
}

// ---------------------------------------------------------------------------
// K2: per-anchor CE + positive loc L1.
// Design (round-3 post-mortem): register staging spilled to scratch; fix is
// ZERO staging registers — global_load_lds DMAs scores straight into
// per-wave LDS strips, double-buffered in LDS, counted s_waitcnt vmcnt(6)
// keeps the next group's DMAs in flight while consuming the current buffer
// (T4: never drain to 0 mid-loop). Wave-private buffers -> no __syncthreads.
// Round-4 hardening: ALL DMAs are full-wave (no exec-divergent
// global_load_lds); the 6th DMA's per-lane source index is clamped in-bounds
// and lanes 16..63 land in the 384-float4 pad region which nothing reads.
// LDS row stride 21 floats: gcd(21,32)=1 -> 2 lanes/bank = conflict-free.
__global__ __launch_bounds__(256) void k_ce(
    const float* __restrict__ plocs,    // [B,A,4]
    const float* __restrict__ pscores,  // [B,A,C]
    const float* __restrict__ boxes,    // [B,M,4] raw pixel xy
    const float* __restrict__ anchors,  // [A,4]
    int*         __restrict__ buf,      // in: packed, out: ce_neg bits
    float*       __restrict__ accf)
{
    __shared__ float4 sb[4][2][384];    // 4 waves x 2 bufs x 6KB = 49152 B

    typedef const void __attribute__((address_space(1))) gv_t;
    typedef void       __attribute__((address_space(3))) lv_t;

    const int t    = threadIdx.x;
    const int lane = t & 63;
    const int wv   = t >> 6;
    const int gw   = blockIdx.x * 4 + wv;      // global wave id
    constexpr int NGW = (B * A / 64) / 4;      // 4366 active waves
    constexpr size_t NF4 = (size_t)B * A * C / 4;  // total float4s in pscores

    float l_pos = 0.f, l_loc = 0.f;

    if (gw < NGW) {                            // wave-uniform guard
        const float4* ps4 = (const float4*)pscores;
        const int g0 = gw * 4;                 // 4 groups of 64 anchors
        float4* lb0 = &sb[wv][0][0];
        float4* lb1 = &sb[wv][1][0];

        // --- stage group g into LDS buffer: 6 full-wave DMA dwordx4 ---
        // (LDS dest = wave-uniform base + lane*16; global src is per-lane)
        auto stage = [&](int g, float4* lds) {
            const size_t gb = (size_t)g * 336;
#pragma unroll
            for (int q = 0; q < 5; ++q)
                __builtin_amdgcn_global_load_lds((gv_t*)(ps4 + gb + q * 64 + lane),
                                                 (lv_t*)(lds + q * 64), 16, 0, 0);
            // 6th round covers float4s 320..335; lanes 16..63 write the pad
            // (320+lane <= 383 < 384) and read a clamped in-bounds address.
            size_t idx = gb + 320 + lane;
            if (idx > NF4 - 1) idx = NF4 - 1;
            __builtin_amdgcn_global_load_lds((gv_t*)(ps4 + idx),
                                             (lv_t*)(lds + 320), 16, 0, 0);
        };

        // prologue: group g0 -> buf0, plus its packed labels
        stage(g0, lb0);
        int pk_cur = buf[(size_t)g0 * 64 + lane];
        int pk_nxt = 0;

#pragma unroll
        for (int k = 0; k < 4; ++k) {
            const int g = g0 + k;

            // issue next group's DMAs first — they stay in flight across the
            // wait below (counted vmcnt, not 0)
            if (k < 3) {
                stage(g + 1, (k & 1) ? lb0 : lb1);
                pk_nxt = buf[(size_t)(g + 1) * 64 + lane];
            }

            // 7 VMEM ops (6 DMAs + 1 pk load) issued for the next group after
            // the current group's 7, so vmcnt(6) guarantees the current
            // buffer + pk_cur are complete while leaving >=6 prefetch ops in
            // flight. Last iter: drain fully.
            if (k < 3) { asm volatile("s_waitcnt vmcnt(6)" ::: "memory"); }
            else       { asm volatile("s_waitcnt vmcnt(0)" ::: "memory"); }

            // consume: stream the row straight from LDS
            const float* row = (const float*)((k & 1) ? lb1 : lb0) + lane * 21;

            const int lab = pk_cur & 255;
            const int obj = pk_cur >> 8;

            float mx = row[0];
#pragma unroll
            for (int c = 1; c < 21; ++c) mx = fmaxf(mx, row[c]);
            float sum = 0.f;
#pragma unroll
            for (int c = 0; c < 21; ++c) sum += __expf(row[c] - mx);
            const float slab = row[lab];       // single dynamic ds_read
            const float ce = mx + __logf(sum) - slab;

            const int flat = g * 64 + lane;
            float cn = ce;
            if (lab != 0) {
                cn = 0.f;
                l_pos += ce;
                const int bi = flat / A;
                const int ai = flat - bi * A;
                const float* bx = boxes + ((size_t)bi * M + obj) * 4;
                const float* an = anchors + (size_t)ai * 4;
                // reference quirk: raw pixel xy boxes fed into cxcy_to_gcxgcy
                float dx = (bx[0] - an[0]) / (an[2] / 10.f);
                float dy = (bx[1] - an[1]) / (an[3] / 10.f);
                float dw = logf(bx[2] / an[2]) * 5.f;
                float dh = logf(bx[3] / an[3]) * 5.f;
                float4 p = ((const float4*)plocs)[flat];
                l_loc += fabsf(p.x - dx) + fabsf(p.y - dy) +
                         fabsf(p.z - dw) + fabsf(p.w - dh);
            }
            ((float*)buf)[flat] = cn;          // coalesced dword store
            pk_cur = pk_nxt;
        }
    }

    // wave reduce; idle waves contribute zero and skip the atomic
    for (int off = 32; off > 0; off >>= 1) {
        l_pos += __shfl_down(l_pos, off);
        l_loc += __shfl_down(l_loc, off);
    }
    if ((t & 63) == 0 && (l_pos != 0.f || l_loc != 0.f)) {
        atomicAdd(&accf[0], l_pos);
        atomicAdd(&accf[1], l_loc);
    }
}

// ---------------------------------------------------------------------------
// K3: per-row sum of top-(3*n_pos[b]) of ce_neg via radix select.
// Exact even with ties: sum = sum(v>t) + (K - cnt_gt) * t.
__global__ __launch_bounds__(1024) void k_topk(
    const float* __restrict__ ce_neg,   // [B,A] (aliased buf)
    const int*   __restrict__ n_pos,    // [B]
    float*       __restrict__ accf)     // accf[2] += row topK sum
{
    __shared__ unsigned int vals[A];
    __shared__ unsigned int hist[256];  // histogram, then suffix sums
    __shared__ unsigned int s_prefix, s_krem;
    __shared__ float        rs[16];
    __shared__ unsigned int rc[16];

    const int b = blockIdx.x;
    const int t = threadIdx.x;
    const int lane = t & 63;
    const int wv   = t >> 6;
    const int K = 3 * n_pos[b];
    const float* row = ce_neg + (size_t)b * A;

    {   // coalesced uint4 load (A = 4*2183, row base 16B-aligned)
        const uint4* r4 = (const uint4*)row;
        uint4* v4 = (uint4*)vals;
        for (int i = t; i < A / 4; i += 1024) v4[i] = r4[i];
    }
    if (t == 0) { s_prefix = 0u; s_krem = (unsigned)K; }
    __syncthreads();

    if (K <= 0) return;  // uniform branch

    if (K >= A) {        // uniform branch: sum the whole row
        float s = 0.f;
        for (int i = t; i < A; i += 1024) s += __uint_as_float(vals[i]);
        for (int off = 32; off > 0; off >>= 1) s += __shfl_down(s, off);
        if (lane == 0) rs[wv] = s;
        __syncthreads();
        if (t == 0) {
            float tot = 0.f;
#pragma unroll
            for (int w = 0; w < 16; w++) tot += rs[w];
            atomicAdd(&accf[2], tot);
        }
        return;
    }

    for (int pass = 0; pass < 4; pass++) {
        const int shift = 24 - 8 * pass;
        const unsigned pref = s_prefix;
        const unsigned krem = s_krem;
        if (t < 256) hist[t] = 0u;
        __syncthreads();
        for (int i = t; i < A; i += 1024) {
            unsigned int v = vals[i];
            if (pass == 0 || (v >> (shift + 8)) == pref)
                atomicAdd(&hist[(v >> shift) & 255u], 1u);
        }
        __syncthreads();
        // wave-0 suffix scan of the 256 bins (hist[i] := sum hist[i..255])
        if (t < 64) {
            unsigned h0 = hist[4 * t + 0], h1 = hist[4 * t + 1];
            unsigned h2 = hist[4 * t + 2], h3 = hist[4 * t + 3];
            unsigned s3 = h3, s2 = h2 + s3, s1 = h1 + s2, s0 = h0 + s1;
            unsigned suf = s0;                 // inclusive suffix of lane totals
            for (int off = 1; off < 64; off <<= 1) {
                unsigned o = __shfl_down(suf, off);
                if (t + off < 64) suf += o;
            }
            unsigned above = suf - s0;         // totals of lanes > t
            hist[4 * t + 0] = above + s0;
            hist[4 * t + 1] = above + s1;
            hist[4 * t + 2] = above + s2;
            hist[4 * t + 3] = above + s3;
        }
        __syncthreads();
        if (t < 256) {
            unsigned ssT = hist[t];
            unsigned ssN = (t < 255) ? hist[t + 1] : 0u;
            if (ssT >= krem && ssN < krem) {   // exactly one thread
                s_prefix = (pref << 8) | (unsigned)t;
                s_krem   = krem - ssN;
            }
        }
        __syncthreads();
    }

    const unsigned int tb = s_prefix;  // bits of the K-th largest value
    float sg = 0.f; unsigned int cg = 0;
    for (int i = t; i < A; i += 1024) {
        unsigned int v = vals[i];
        if (v > tb) { sg += __uint_as_float(v); cg++; }
    }
    for (int off = 32; off > 0; off >>= 1) {
        sg += __shfl_down(sg, off);
        cg += __shfl_down(cg, off);
    }
    if (lane == 0) { rs[wv] = sg; rc[wv] = cg; }
    __syncthreads();
    if (t == 0) {
        float tv = __uint_as_float(tb);
        float tot = 0.f; unsigned cnt = 0;
#pragma unroll
        for (int w = 0; w < 16; w++) { tot += rs[w]; cnt += rc[w]; }
        atomicAdd(&accf[2], tot + (float)(K - (int)cnt) * tv);
    }
}

// ---------------------------------------------------------------------------
// K4: final scalar
__global__ void k_final(const float* __restrict__ accf,
                        const int* __restrict__ npt,
                        float* __restrict__ out)
{
    float n = (float)(*npt);
    float conf_loss = (accf[2] + accf[0]) / n;
    float loc_loss  = accf[1] / (n * 4.f);
    out[0] = conf_loss + loc_loss;
}

// ---------------------------------------------------------------------------
extern "C" void kernel_launch(void* const* d_in, const int* in_sizes, int n_in,
                              void* d_out, int out_size, void* d_ws, size_t ws_size,
                              hipStream_t stream)
{
    const float* plocs   = (const float*)d_in[0];  // [B,A,4]
    const float* pscores = (const float*)d_in[1];  // [B,A,C]
    const float* boxes   = (const float*)d_in[2];  // [B,M,4]
    const int*   labels  = (const int*)d_in[3];    // [B,M]
    const float* anchors = (const float*)d_in[4];  // [A,4]
    float*       out     = (float*)d_out;

    // workspace layout (4-byte elements):
    // [0..2] accf, [3] n_pos_total, [8..8+B) n_pos, [8+B ..) packed/ce_neg [B*A]
    // buf offset = (8+B)*4 = 544 bytes -> 16B-aligned for int4/float4 access
    float* accf  = (float*)d_ws;
    int*   npt   = (int*)d_ws + 3;
    int*   n_pos = (int*)d_ws + 8;
    int*   buf   = (int*)d_ws + 8 + B;

    k_init<<<1, 64, 0, stream>>>(accf, npt);
    k_match<<<B, 1024, 0, stream>>>(boxes, labels, anchors, buf, n_pos, npt);
    constexpr int NBW = ((B * A / 64) / 4 + 3) / 4;   // 1092 blocks of 4 waves
    k_ce<<<NBW, 256, 0, stream>>>(plocs, pscores, boxes, anchors, buf, accf);
    k_topk<<<B, 1024, 0, stream>>>((const float*)buf, n_pos, accf);
    k_final<<<1, 1, 0, stream>>>(accf, npt, out);
}

// Round 6
// 289.455 us; speedup vs baseline: 1.0754x; 1.0183x over previous
//
#include <hip/hip_runtime.h>
#include <hip/hip_bf16.h>

// Problem constants (from reference setup_inputs)
constexpr int B = 128;
constexpr int A = 8732;
constexpr int C = 21;
constexpr int M = 8;

// workspace layout (4-byte elements):
// [0..2] accf  (0=conf_pos, 1=loc_sum, 2=conf_hard_neg)
// [3]    done  (k_topk completion counter)
// [4]    npt   (n_pos_total, written by k_ce block 0)
// [8..8+B)  n_pos
// [8+B ..)  packed/ce_neg buf [B*A]   (offset 544 B -> 16B aligned)

// ---------------------------------------------------------------------------
// K1: per-batch matching. One block (1024 threads) per batch row.
// Block 0 additionally zeroes the accumulators + completion counter (safe:
// nothing in k_match reads them; k_ce/k_topk run in later dispatches).
__global__ __launch_bounds__(1024) void k_match(
    const float* __restrict__ boxes,    // [B,M,4] raw pixel xy
    const int*   __restrict__ labels,   // [B,M]
    const float* __restrict__ anchors,  // [A,4] cxcy
    int*         __restrict__ packed,   // [B,A]  lab | (obj<<8)
    int*         __restrict__ n_pos,    // [B]
    float*       __restrict__ accf,
    int*         __restrict__ done)
{
    __shared__ float         s_iou[A];
    __shared__ unsigned char s_obj[A];
    __shared__ float s_pv[M][16];
    __shared__ int   s_pi[M][16];
    __shared__ int   s_force[M];
    __shared__ int   s_c[16];
    __shared__ float s_box[M][4];
    __shared__ int   s_lab[M];

    const int b = blockIdx.x;
    const int t = threadIdx.x;
    const int lane = t & 63;
    const int wv   = t >> 6;          // 0..15

    if (b == 0 && t == 0) {           // zero accumulators for this iteration
        accf[0] = 0.f; accf[1] = 0.f; accf[2] = 0.f; *done = 0;
    }

    if (t < M * 4) ((float*)s_box)[t] = boxes[b * M * 4 + t];
    if (t < M)     s_lab[t] = labels[b * M + t];
    __syncthreads();

    // scaled boxes (match reference: boxes / 300.0) + areas
    float bb[M][4], barea[M];
#pragma unroll
    for (int m = 0; m < M; m++) {
        bb[m][0] = s_box[m][0] / 300.f;
        bb[m][1] = s_box[m][1] / 300.f;
        bb[m][2] = s_box[m][2] / 300.f;
        bb[m][3] = s_box[m][3] / 300.f;
        barea[m] = (bb[m][2] - bb[m][0]) * (bb[m][3] - bb[m][1]);
    }

    float bestv[M];
    int   besti[M];
#pragma unroll
    for (int m = 0; m < M; m++) { bestv[m] = -1.f; besti[m] = 0; }

    const float4* anch4 = (const float4*)anchors;
    for (int a = t; a < A; a += 1024) {
        float4 an = anch4[a];
        float ax1 = an.x - an.z / 2.0f, ay1 = an.y - an.w / 2.0f;
        float ax2 = an.x + an.z / 2.0f, ay2 = an.y + an.w / 2.0f;
        float aarea = (ax2 - ax1) * (ay2 - ay1);

        float bmax = -1.f; int bm = 0;
#pragma unroll
        for (int m = 0; m < M; m++) {
            float lx = fmaxf(bb[m][0], ax1), ly = fmaxf(bb[m][1], ay1);
            float rx = fminf(bb[m][2], ax2), ry = fminf(bb[m][3], ay2);
            float iw = fmaxf(rx - lx, 0.f), ih = fmaxf(ry - ly, 0.f);
            float inter = iw * ih;
            float iou = inter / (barea[m] + aarea - inter);
            if (iou > bmax) { bmax = iou; bm = m; }               // first-max over m
            if (iou > bestv[m]) { bestv[m] = iou; besti[m] = a; } // first-max over a (ascending)
        }
        s_iou[a] = bmax;
        s_obj[a] = (unsigned char)bm;
    }

    // per-object argmax: wave shuffle reduce (tie-break: smaller anchor index)
#pragma unroll
    for (int m = 0; m < M; m++) {
        float v = bestv[m]; int i = besti[m];
        for (int off = 32; off > 0; off >>= 1) {
            float ov = __shfl_down(v, off);
            int   oi = __shfl_down(i, off);
            if (ov > v || (ov == v && oi < i)) { v = ov; i = oi; }
        }
        if (lane == 0) { s_pv[m][wv] = v; s_pi[m][wv] = i; }
    }
    __syncthreads();

    if (t < M) {
        float bv = -1.f; int bi = 0x7fffffff;
#pragma unroll
        for (int w = 0; w < 16; w++) {
            float v = s_pv[t][w]; int i = s_pi[t][w];
            if (v > bv || (v == bv && i < bi)) { bv = v; bi = i; }
        }
        s_force[t] = bi;
    }
    __syncthreads();

    // numpy fancy-assign semantics: last object wins on duplicate anchors
    if (t == 0) {
        for (int m = 0; m < M; m++) {
            int a = s_force[m];
            s_obj[a] = (unsigned char)m;
            s_iou[a] = 1.0f;
        }
    }
    __syncthreads();

    int cnt = 0;
    for (int a = t; a < A; a += 1024) {
        int obj = s_obj[a];
        int lab = s_lab[obj];
        if (s_iou[a] < 0.5f) lab = 0;
        packed[(size_t)b * A + a] = lab | (obj << 8);
        if (lab != 0) cnt++;
    }
    for (int off = 32; off > 0; off >>= 1) cnt += __shfl_down(cnt, off);
    if (lane == 0) s_c[wv] = cnt;
    __syncthreads();
    if (t == 0) {
        int c0 = 0;
#pragma unroll
        for (int w = 0; w < 16; w++) c0 += s_c[w];
        n_pos[b] = c0;
    }
}

// ---------------------------------------------------------------------------
// K2: per-anchor CE + positive loc L1. One thread per 4 consecutive anchors:
// 84 floats = 21 aligned float4 loads (R0 form — best measured k_ce, 122 µs).
// Block 0's first wave additionally reduces n_pos -> npt (n_pos is complete:
// it was written by k_match, a prior dispatch).
__global__ __launch_bounds__(256) void k_ce(
    const float* __restrict__ plocs,    // [B,A,4]
    const float* __restrict__ pscores,  // [B,A,C]
    const float* __restrict__ boxes,    // [B,M,4] raw pixel xy
    const float* __restrict__ anchors,  // [A,4]
    int*         __restrict__ buf,      // in: packed, out: ce_neg bits
    float*       __restrict__ accf,
    const int*   __restrict__ n_pos,    // [B]
    int*         __restrict__ npt)      // out: n_pos_total
{
    if (blockIdx.x == 0 && threadIdx.x < 64) {
        int v = n_pos[threadIdx.x] + n_pos[threadIdx.x + 64];
        for (int off = 32; off > 0; off >>= 1) v += __shfl_down(v, off);
        if (threadIdx.x == 0) *npt = v;
    }

    constexpr int NQ = B * A / 4;       // 279424 quads
    const int i4 = blockIdx.x * 256 + threadIdx.x;
    float l_pos = 0.f, l_loc = 0.f;

    if (i4 < NQ) {
        const int base = i4 * 4;        // flat anchor index of quad start
        const float4* s4 = (const float4*)(pscores + (size_t)base * C);
        float4 v[21];
#pragma unroll
        for (int i = 0; i < 21; i++) v[i] = s4[i];   // 336 B contiguous
        const float* f = (const float*)v;            // 84 floats

        int4 pk4 = ((const int4*)buf)[i4];
        const int pks[4] = {pk4.x, pk4.y, pk4.z, pk4.w};

        const int b = base / A;
        const int a0 = base - b * A;

        float4 cn4;
        float* cn = (float*)&cn4;
#pragma unroll
        for (int j = 0; j < 4; j++) {
            const float* row = f + j * C;
            const int lab = pks[j] & 255;
            const int obj = pks[j] >> 8;

            float mx = row[0];
#pragma unroll
            for (int c = 1; c < C; c++) mx = fmaxf(mx, row[c]);
            float sum = 0.f, slab = 0.f;
#pragma unroll
            for (int c = 0; c < C; c++) {
                sum += __expf(row[c] - mx);
                if (c == lab) slab = row[c];
            }
            float ce = mx + __logf(sum) - slab;

            cn[j] = ce;
            if (lab != 0) {
                cn[j] = 0.f;
                l_pos += ce;
                const float* bx = boxes + ((size_t)b * M + obj) * 4;
                const float* an = anchors + (size_t)(a0 + j) * 4;
                // reference quirk: raw pixel xy boxes fed into cxcy_to_gcxgcy
                float dx = (bx[0] - an[0]) / (an[2] / 10.f);
                float dy = (bx[1] - an[1]) / (an[3] / 10.f);
                float dw = logf(bx[2] / an[2]) * 5.f;
                float dh = logf(bx[3] / an[3]) * 5.f;
                float4 p = ((const float4*)plocs)[base + j];
                l_loc += fabsf(p.x - dx) + fabsf(p.y - dy) +
                         fabsf(p.z - dw) + fabsf(p.w - dh);
            }
        }
        ((float4*)buf)[i4] = cn4;
    }

    // wave reduce; positives are rare so atomics are rare
    for (int off = 32; off > 0; off >>= 1) {
        l_pos += __shfl_down(l_pos, off);
        l_loc += __shfl_down(l_loc, off);
    }
    if ((threadIdx.x & 63) == 0 && (l_pos != 0.f || l_loc != 0.f)) {
        atomicAdd(&accf[0], l_pos);
        atomicAdd(&accf[1], l_loc);
    }
}

// ---------------------------------------------------------------------------
// K3: per-row sum of top-(3*n_pos[b]) of ce_neg via radix select, FUSED with
// the final scalar (completion-counter pattern; device-scope atomics).
// Histogram fix: CE values concentrate in 2-3 top-byte bins (floats in
// ~[1,16) -> exponent byte 0x3F-0x41), so a single shared histogram
// serialized ~8732 same-address LDS atomics 16 waves deep. Per-wave
// histograms whist[16][257] (257 = bank-rotate per wave: addr 257w+b ->
// bank (w+b)%32) keep waves on distinct banks; merge before the scan.
// Exact even with ties: sum = sum(v>t) + (K - cnt_gt) * t.
__global__ __launch_bounds__(1024) void k_topk(
    const float* __restrict__ ce_neg,   // [B,A] (aliased buf)
    const int*   __restrict__ n_pos,    // [B]
    const int*   __restrict__ npt,      // n_pos_total (from k_ce)
    float*       __restrict__ accf,     // accf[2] += row topK sum
    int*         __restrict__ done,     // completion counter (zeroed by k_match)
    float*       __restrict__ out)
{
    __shared__ unsigned int vals[A];
    __shared__ unsigned int hist[256];      // merged histogram -> suffix sums
    __shared__ unsigned int whist[16][257]; // per-wave histograms (padded)
    __shared__ unsigned int s_prefix, s_krem;
    __shared__ float        rs[16];
    __shared__ unsigned int rc[16];

    const int b = blockIdx.x;
    const int t = threadIdx.x;
    const int lane = t & 63;
    const int wv   = t >> 6;
    const int K = 3 * n_pos[b];
    const float* row = ce_neg + (size_t)b * A;

    {   // coalesced uint4 load (A = 4*2183, row base 16B-aligned)
        const uint4* r4 = (const uint4*)row;
        uint4* v4 = (uint4*)vals;
        for (int i = t; i < A / 4; i += 1024) v4[i] = r4[i];
    }
    if (t == 0) { s_prefix = 0u; s_krem = (unsigned)K; }
    __syncthreads();

    float blockSum = 0.f;                   // valid at t==0

    if (K >= A) {        // uniform branch: sum the whole row
        float s = 0.f;
        for (int i = t; i < A; i += 1024) s += __uint_as_float(vals[i]);
        for (int off = 32; off > 0; off >>= 1) s += __shfl_down(s, off);
        if (lane == 0) rs[wv] = s;
        __syncthreads();
        if (t == 0) {
            float tot = 0.f;
#pragma unroll
            for (int w = 0; w < 16; w++) tot += rs[w];
            blockSum = tot;
        }
    } else if (K > 0) {
        for (int pass = 0; pass < 4; pass++) {
            const int shift = 24 - 8 * pass;
            const unsigned pref = s_prefix;
            const unsigned krem = s_krem;
            // zero per-wave histograms
            unsigned* wf = &whist[0][0];
            for (int i = t; i < 16 * 257; i += 1024) wf[i] = 0u;
            __syncthreads();
            for (int i = t; i < A; i += 1024) {
                unsigned int v = vals[i];
                if (pass == 0 || (v >> (shift + 8)) == pref)
                    atomicAdd(&whist[wv][(v >> shift) & 255u], 1u);
            }
            __syncthreads();
            // merge 16 per-wave hists (lanes read distinct banks, 2/bank)
            if (t < 256) {
                unsigned s = 0;
#pragma unroll
                for (int w = 0; w < 16; w++) s += whist[w][t];
                hist[t] = s;
            }
            __syncthreads();
            // wave-0 suffix scan of the 256 bins (hist[i] := sum hist[i..255])
            if (t < 64) {
                unsigned h0 = hist[4 * t + 0], h1 = hist[4 * t + 1];
                unsigned h2 = hist[4 * t + 2], h3 = hist[4 * t + 3];
                unsigned s3 = h3, s2 = h2 + s3, s1 = h1 + s2, s0 = h0 + s1;
                unsigned suf = s0;                 // inclusive suffix of lane totals
                for (int off = 1; off < 64; off <<= 1) {
                    unsigned o = __shfl_down(suf, off);
                    if (t + off < 64) suf += o;
                }
                unsigned above = suf - s0;         // totals of lanes > t
                hist[4 * t + 0] = above + s0;
                hist[4 * t + 1] = above + s1;
                hist[4 * t + 2] = above + s2;
                hist[4 * t + 3] = above + s3;
            }
            __syncthreads();
            if (t < 256) {
                unsigned ssT = hist[t];
                unsigned ssN = (t < 255) ? hist[t + 1] : 0u;
                if (ssT >= krem && ssN < krem) {   // exactly one thread
                    s_prefix = (pref << 8) | (unsigned)t;
                    s_krem   = krem - ssN;
                }
            }
            __syncthreads();
        }

        const unsigned int tb = s_prefix;  // bits of the K-th largest value
        float sg = 0.f; unsigned int cg = 0;
        for (int i = t; i < A; i += 1024) {
            unsigned int v = vals[i];
            if (v > tb) { sg += __uint_as_float(v); cg++; }
        }
        for (int off = 32; off > 0; off >>= 1) {
            sg += __shfl_down(sg, off);
            cg += __shfl_down(cg, off);
        }
        if (lane == 0) { rs[wv] = sg; rc[wv] = cg; }
        __syncthreads();
        if (t == 0) {
            float tv = __uint_as_float(tb);
            float tot = 0.f; unsigned cnt = 0;
#pragma unroll
            for (int w = 0; w < 16; w++) { tot += rs[w]; cnt += rc[w]; }
            blockSum = tot + (float)(K - (int)cnt) * tv;
        }
    }
    // K <= 0: blockSum stays 0, still participate in completion protocol.

    if (t == 0) {
        if (blockSum != 0.f) atomicAdd(&accf[2], blockSum);
        __threadfence();                       // order my add before the count
        unsigned old = atomicAdd((unsigned*)done, 1u);
        if (old == (unsigned)(B - 1)) {        // last block: final scalar
            float cpos = atomicAdd(&accf[0], 0.f);   // device-coherent reads
            float lsum = atomicAdd(&accf[1], 0.f);
            float chn  = atomicAdd(&accf[2], 0.f);
            float n = (float)(*npt);
            out[0] = (chn + cpos) / n + lsum / (n * 4.f);
        }
    }
}

// ---------------------------------------------------------------------------
extern "C" void kernel_launch(void* const* d_in, const int* in_sizes, int n_in,
                              void* d_out, int out_size, void* d_ws, size_t ws_size,
                              hipStream_t stream)
{
    const float* plocs   = (const float*)d_in[0];  // [B,A,4]
    const float* pscores = (const float*)d_in[1];  // [B,A,C]
    const float* boxes   = (const float*)d_in[2];  // [B,M,4]
    const int*   labels  = (const int*)d_in[3];    // [B,M]
    const float* anchors = (const float*)d_in[4];  // [A,4]
    float*       out     = (float*)d_out;

    float* accf  = (float*)d_ws;
    int*   done  = (int*)d_ws + 3;
    int*   npt   = (int*)d_ws + 4;
    int*   n_pos = (int*)d_ws + 8;
    int*   buf   = (int*)d_ws + 8 + B;

    k_match<<<B, 1024, 0, stream>>>(boxes, labels, anchors, buf, n_pos, accf, done);
    constexpr int NQ = B * A / 4;
    k_ce<<<(NQ + 255) / 256, 256, 0, stream>>>(plocs, pscores, boxes, anchors,
                                               buf, accf, n_pos, npt);
    k_topk<<<B, 1024, 0, stream>>>((const float*)buf, n_pos, npt, accf, done, out);
}